// Round 8
// baseline (232.072 us; speedup 1.0000x reference)
//
#include <hip/hip_runtime.h>
#include <math.h>

#define BB 16
#define NN 2048
#define FF 64
#define SS 4
#define PP 22
#define OO 42
#define FPDIM (FF + 2*PP)   // 108
#define NREG 24             // d2 values kept in VGPRs per lane
#define NLDS 8              // d2 values kept in LDS rows per lane (NREG+NLDS = 2048/64)

__device__ __forceinline__ float readfirstlane_f32(float v) {
    // value-preserving wave-uniform broadcast (builtin is int->int; must pass bits!)
    return __uint_as_float((unsigned)__builtin_amdgcn_readfirstlane((int)__float_as_uint(v)));
}

// ---------------- Kernel 1: coords = x@W_s + b_s ; feats = x@W_f + b_f ; WoT = Wo^T ----------------
__global__ __launch_bounds__(256) void precompute_kernel(
    const float* __restrict__ x, const float* __restrict__ Ws, const float* __restrict__ bs,
    const float* __restrict__ Wf, const float* __restrict__ bf, const float* __restrict__ Wo,
    float* __restrict__ coords, float* __restrict__ feats, float* __restrict__ WoT)
{
    int row = blockIdx.x * 256 + threadIdx.x;   // 0 .. B*N-1
    if (blockIdx.x == 0) {                       // transpose Wo [108][42] -> WoT [42][108]
        for (int idx = threadIdx.x; idx < FPDIM * OO; idx += 256) {
            int k = idx / OO, o = idx - k * OO;
            WoT[o * FPDIM + k] = Wo[idx];
        }
    }
    if (row >= BB * NN) return;

    const float4* x4 = (const float4*)(x + (size_t)row * FF);
    float c0 = bs[0], c1 = bs[1], c2 = bs[2], c3 = bs[3];
    float f[PP];
    #pragma unroll
    for (int c = 0; c < PP; c++) f[c] = bf[c];

    #pragma unroll
    for (int k4 = 0; k4 < FF / 4; k4++) {
        float4 xv = x4[k4];
        float xs[4] = {xv.x, xv.y, xv.z, xv.w};
        #pragma unroll
        for (int r = 0; r < 4; r++) {
            int k = k4 * 4 + r;
            float xk = xs[r];
            c0 = fmaf(xk, Ws[k * SS + 0], c0);
            c1 = fmaf(xk, Ws[k * SS + 1], c1);
            c2 = fmaf(xk, Ws[k * SS + 2], c2);
            c3 = fmaf(xk, Ws[k * SS + 3], c3);
            #pragma unroll
            for (int c = 0; c < PP; c++) f[c] = fmaf(xk, Wf[k * PP + c], f[c]);
        }
    }
    float4* cp = (float4*)(coords + (size_t)row * SS);
    *cp = make_float4(c0, c1, c2, c3);
    float* fo = feats + (size_t)row * PP;
    #pragma unroll
    for (int c = 0; c < PP; c++) fo[c] = f[c];
}

// ---------------- Kernel 2: wave-per-query kNN + aggregate + fused output matvec/tanh ----------------
// (128,4): 4 blocks x 2 waves = 8 waves/EU -> 64-VGPR budget (R5/R7 calibration).
// 24 d2 in VGPRs + 8 rows per-wave LDS; counting bisection; lane-local scan collect.
__global__ __launch_bounds__(128, 4) void knn_out_kernel(
    const float* __restrict__ coords, const float* __restrict__ feats,
    const float* __restrict__ x, const float* __restrict__ WoT, const float* __restrict__ bo,
    const int* __restrict__ nnbr, float* __restrict__ out)
{
    const int lane = threadIdx.x & 63;
    const int w    = threadIdx.x >> 6;
    const int q    = blockIdx.x * 2 + w;       // 0..32767
    const int b    = q >> 11;
    const int i    = q & (NN - 1);

    int K = *nnbr; K = K < 2 ? 2 : (K > 64 ? 64 : K);

    __shared__ float d2x[2][NLDS * 64];           // 2 KB per wave
    __shared__ int   isel[2][64];
    __shared__ float wsel[2][64];
    __shared__ unsigned long long candk[2][64];   // (d2bits<<32)|j packed keys
    __shared__ __align__(16) float urow[2][112];  // [x | max | mean], 108 used

    const float4* cb = (const float4*)(coords + (size_t)b * NN * SS);
    float4 qv = cb[i];
    const float qx = readfirstlane_f32(qv.x);
    const float qy = readfirstlane_f32(qv.y);
    const float qz = readfirstlane_f32(qv.z);
    const float qw = readfirstlane_f32(qv.w);

    // ---- distances: 24 in VGPRs, 8 rows in LDS; track per-lane min ----
    float d2r[NREG];
    float lmin = INFINITY;
    #pragma unroll
    for (int r = 0; r < NREG; r++) {
        float4 c = cb[r * 64 + lane];
        float d0 = qx - c.x, d1 = qy - c.y, d2 = qz - c.z, d3 = qw - c.w;
        float v = d0 * d0 + d1 * d1 + d2 * d2 + d3 * d3;
        d2r[r] = v;
        lmin = fminf(lmin, v);
    }
    #pragma unroll 2
    for (int r = NREG; r < 32; r++) {
        float4 c = cb[r * 64 + lane];
        float d0 = qx - c.x, d1 = qy - c.y, d2 = qz - c.z, d3 = qw - c.w;
        float v = d0 * d0 + d1 * d1 + d2 * d2 + d3 * d3;
        d2x[w][(r - NREG) * 64 + lane] = v;
        lmin = fminf(lmin, v);
    }
    // stage x row for the epilogue (coalesced 256B per wave)
    urow[w][lane] = x[((size_t)b * NN + i) * FF + lane];
    __builtin_amdgcn_wave_barrier();

    // ---- first-probe estimator: mean of per-lane minima ~ K/N quantile ----
    float s = lmin;
    #pragma unroll
    for (int off = 1; off < 64; off <<= 1) s += __shfl_xor(s, off, 64);
    float t0 = s * (1.0f / 64.0f);

    // ---- bisection on the threshold: invariant cnt_lt(lo) < K <= cnt_lt(hi) ----
    unsigned loU = 0u, hiU = 0x7F800000u;   // [0, +inf)
    int cLo = 0, cHi = NN;
    float tPrev = t0; int cPrev = -1;
    int probes = 0;
    while (cHi - cLo > 64 && hiU - loU > 1u && probes < 34) {
        unsigned tU;
        if (probes == 0 && t0 > 0.f) {
            tU = __float_as_uint(t0);
        } else if (cPrev > 0 && probes < 8) {
            // local power law F(x) ~ x^2  ->  aim t' = t * sqrt(K/c)
            float g = tPrev * __fsqrt_rn((float)K / (float)cPrev);
            tU = __float_as_uint(g);
        } else if (cPrev == 0 && probes < 8) {
            tU = __float_as_uint(tPrev * 4.0f);
        } else {
            tU = loU + ((hiU - loU) >> 1);
        }
        if (tU <= loU || tU >= hiU) tU = loU + ((hiU - loU) >> 1);   // guaranteed shrink
        float t = __uint_as_float(tU);
        int c = 0;
        #pragma unroll
        for (int r = 0; r < NREG; r++) c += (d2r[r] < t) ? 1 : 0;
        #pragma unroll
        for (int r8 = 0; r8 < NLDS; r8++) c += (d2x[w][r8 * 64 + lane] < t) ? 1 : 0;
        #pragma unroll
        for (int off = 1; off < 64; off <<= 1) c += __shfl_xor(c, off, 64);
        if (c >= K) { hiU = tU; cHi = c; } else { loU = tU; cLo = c; }
        tPrev = t; cPrev = c;
        probes++;
    }

    const float lo = __uint_as_float(loU);
    const float hi = __uint_as_float(hiU);
    const int  need = K - cLo;              // in [1, K]; window holds >= need values

    // ---- collect, two-phase lane-local: count -> packed wave scan -> sequential writes ----
    __builtin_amdgcn_wave_barrier();
    int c1 = 0, c2 = 0;
    #pragma unroll
    for (int r = 0; r < 32; r++) {
        float v = (r < NREG) ? d2r[r] : d2x[w][(r - NREG) * 64 + lane];
        int j = r * 64 + lane;
        c1 += ((v < lo) & (j != i)) ? 1 : 0;
        c2 += ((v >= lo) & (v < hi)) ? 1 : 0;
    }
    int pk = c1 | (c2 << 16);
    int inc = pk;
    #pragma unroll
    for (int off = 1; off < 64; off <<= 1) {
        int t2 = __shfl_up(inc, off, 64);
        if (lane >= off) inc += t2;
    }
    int excl = inc - pk;
    int tot  = __shfl(inc, 63, 64);
    int b1 = excl & 0xFFFF;            // per-lane write base, below-window
    int b2 = excl >> 16;               // per-lane write base, candidates
    const int nbelow = tot & 0xFFFF;   // <= K-1
    int ecand = tot >> 16; if (ecand > 64) ecand = 64;
    #pragma unroll
    for (int r = 0; r < 32; r++) {
        float v = (r < NREG) ? d2r[r] : d2x[w][(r - NREG) * 64 + lane];
        int j = r * 64 + lane;
        if ((v < lo) & (j != i)) { isel[w][b1] = j; wsel[w][b1] = v; b1++; }
        else if ((v >= lo) & (v < hi)) { if (b2 < 64) candk[w][b2] = ((unsigned long long)__float_as_uint(v) << 32) | (unsigned)j; b2++; }
    }
    __builtin_amdgcn_wave_barrier();

    // ---- rank candidates by (value, index); append `need` smallest, skipping self ----
    int nsel;
    {
        unsigned long long mykey = ~0ull;
        if (lane < ecand) mykey = candk[w][lane];
        int mr = 0;
        for (int u = 0; u < ecand; u++) {        // ds_read_b64 broadcast, conflict-free
            unsigned long long k2 = candk[w][u];
            mr += (k2 < mykey) ? 1 : 0;
        }
        int mj = (int)(mykey & 0xFFFFFFFFull);
        bool ps = (lane < ecand) & (mr < need) & (mj != i);
        unsigned long long ms = __ballot(ps);
        if (ps) {
            int slot = nbelow + __popcll(ms & ((1ull << lane) - 1ull));
            if (slot < 64) { isel[w][slot] = mj; wsel[w][slot] = __uint_as_float((unsigned)(mykey >> 32)); }
        }
        nsel = nbelow + __popcll(ms);
        if (nsel > 64) nsel = 64;                // expect K-1 = 39
    }
    __builtin_amdgcn_wave_barrier();
    if (lane < nsel) wsel[w][lane] = __expf(-wsel[w][lane]);
    __builtin_amdgcn_wave_barrier();

    // ---- weighted max / mean: lanes 0-21 do even m, lanes 32-53 odd m ----
    const float* fb = feats + (size_t)b * NN * PP;
    int g = lane >> 5, c = lane & 31;
    float mx = -INFINITY, sm = 0.f;
    if (c < PP) {
        for (int m = g; m < nsel; m += 2) {
            int j = isel[w][m]; float wt = wsel[w][m];
            float f = fb[(size_t)j * PP + c];
            float wf = wt * f;
            mx = fmaxf(mx, wf); sm += wf;
        }
    }
    float mx2 = __shfl_xor(mx, 32, 64);
    float sm2 = __shfl_xor(sm, 32, 64);
    mx = fmaxf(mx, mx2); sm += sm2;
    if (g == 0 && c < PP) {
        urow[w][FF + c]      = mx;
        urow[w][FF + PP + c] = sm / (float)(K - 1);
    }
    __builtin_amdgcn_wave_barrier();

    // ---- fused epilogue: out[q][o] = tanh(urow . WoT[o] + bo[o]), lanes 0-41 ----
    if (lane < OO) {
        float acc = bo[lane];
        const float4* wr = (const float4*)(WoT + (size_t)lane * FPDIM);
        #pragma unroll 9
        for (int k4 = 0; k4 < FPDIM / 4; k4++) {
            float4 u  = *((const float4*)&urow[w][k4 * 4]);   // ds_read_b128 broadcast
            float4 ww = wr[k4];                               // global float4, L1-resident
            acc = fmaf(u.x, ww.x, acc);
            acc = fmaf(u.y, ww.y, acc);
            acc = fmaf(u.z, ww.z, acc);
            acc = fmaf(u.w, ww.w, acc);
        }
        float a = acc < -12.f ? -12.f : (acc > 12.f ? 12.f : acc);
        float e2 = __expf(2.f * a);
        out[(size_t)q * OO + lane] = (e2 - 1.f) / (e2 + 1.f);
    }
}

extern "C" void kernel_launch(void* const* d_in, const int* in_sizes, int n_in,
                              void* d_out, int out_size, void* d_ws, size_t ws_size,
                              hipStream_t stream) {
    const float* x  = (const float*)d_in[0];
    const float* Ws = (const float*)d_in[1];
    const float* bs = (const float*)d_in[2];
    const float* Wf = (const float*)d_in[3];
    const float* bf = (const float*)d_in[4];
    const float* Wo = (const float*)d_in[5];
    const float* bo = (const float*)d_in[6];
    const int*   nn = (const int*)d_in[7];
    float* out = (float*)d_out;

    float* coords = (float*)d_ws;                              // 16*2048*4  = 512 KB
    float* feats  = coords + (size_t)BB * NN * SS;             // 16*2048*22 = 2.75 MB
    float* WoT    = feats  + (size_t)BB * NN * PP;             // 42*108 floats = 18 KB

    precompute_kernel<<<(BB * NN) / 256, 256, 0, stream>>>(x, Ws, bs, Wf, bf, Wo, coords, feats, WoT);
    knn_out_kernel<<<(BB * NN) / 2, 128, 0, stream>>>(coords, feats, x, WoT, bo, nn, out);
}